// Round 1
// baseline (131.987 us; speedup 1.0000x reference)
//
#include <hip/hip_runtime.h>

#define NB 32
#define NA 3
#define NGH 76
#define NGW 76
#define NT 48
#define PLANE (NGH * NGW)         // 5776
#define NCELL (NB * NA * PLANE)   // 554496
#define NOUT  (NCELL * 6)         // 3326976

static_assert(NCELL % 256 == 0, "grid must divide evenly");

// ---------------- Kernel 1: per-target prep (48 targets) ----------------
// tinfo layout per target (16 floats):
// 0: timg  1: valid  2: bi  3: gj  4: gi  5: tx  6: ty  7: tw  8: th  9: sc
// 10..13: x1 y1 x2 y2 (normalized xyxy)  14: area  15: pad
__global__ void yolo_prep(const float* __restrict__ tgt,
                          float* __restrict__ tinfo,
                          float* __restrict__ lossbuf) {
    const int t = threadIdx.x;
    if (t < 4) lossbuf[1 + t] = 0.0f;   // zero the 4 partial-loss accumulators
    if (t >= NT) return;

    const float aw_px[9] = {10.f,16.f,33.f,30.f,62.f,59.f,116.f,156.f,373.f};
    const float ah_px[9] = {13.f,30.f,23.f,61.f,45.f,119.f,90.f,198.f,326.f};

    const float t00 = tgt[0];
    const float* tr = tgt + t * 6;
    const int   timg = (int)(tr[0] - t00);
    const float bxn = tr[1], byn = tr[2], bwn = tr[3], bhn = tr[4];

    const float gx = bxn * (float)NGW;
    const float gy = byn * (float)NGH;
    const int gi = (int)gx;
    const int gj = (int)gy;
    const float tarea = bwn * bhn;

    // anchor wh-IoU argmax over 9 anchors (first max wins, strict >)
    int bidx = 0; float biou = -1e30f;
    for (int k = 0; k < 9; ++k) {
        const float aw = aw_px[k] / 608.0f;
        const float ah = ah_px[k] / 608.0f;
        const float wi = fminf(aw, bwn) * fminf(ah, bhn);
        const float un = ((aw * ah + 1e-16f) + tarea) - wi;
        const float iou = wi / un;
        if (iou > biou) { biou = iou; bidx = k; }
    }
    const bool inm = (bidx >= 0) && (bidx <= 2);     // MASK = {0,1,2}
    const bool valid = inm && (gi < NGW) && (gj < NGH) && (gi >= 0) && (gj >= 0);
    const int bi = bidx;
    const int bic = bi < 0 ? 0 : (bi > 2 ? 2 : bi);  // jax clamps OOB gather

    const float apw[3] = {10.f, 16.f, 33.f};
    const float aph[3] = {13.f, 30.f, 23.f};
    const float tx = gx - floorf(gx);
    const float ty = gy - floorf(gy);
    const float tw = logf(((bwn * (float)NGW) * 8.0f) / apw[bic] + 1e-16f);
    const float th = logf(((bhn * (float)NGH) * 8.0f) / aph[bic] + 1e-16f);
    const float sc = 2.0f - bwn * bhn;

    float* o = tinfo + t * 16;
    o[0]  = (float)timg;
    o[1]  = valid ? 1.0f : 0.0f;
    o[2]  = (float)bi;
    o[3]  = (float)gj;
    o[4]  = (float)gi;
    o[5]  = tx;  o[6] = ty;  o[7] = tw;  o[8] = th;  o[9] = sc;
    o[10] = bxn - bwn * 0.5f;
    o[11] = byn - bhn * 0.5f;
    o[12] = bxn + bwn * 0.5f;
    o[13] = byn + bhn * 0.5f;
    o[14] = tarea;
    o[15] = 0.0f;
}

// ---------------- Kernel 2: per-cell decode + losses ----------------
__launch_bounds__(256)
__global__ void yolo_main(const float* __restrict__ x,
                          const float* __restrict__ tinfo,
                          float* __restrict__ out,
                          float* __restrict__ lossbuf) {
    __shared__ float st[NT * 16];
    for (int i = threadIdx.x; i < NT * 16; i += 256) st[i] = tinfo[i];
    __syncthreads();

    const int tid = blockIdx.x * 256 + threadIdx.x;   // == cell linear index
    float lxy = 0.f, lwh = 0.f, lconf = 0.f, lcls = 0.f;
    {
        const int gw = tid % NGW;
        const int gh = (tid / NGW) % NGH;
        const int a  = (tid / PLANE) % NA;
        const int b  = tid / (NA * PLANE);

        const float* xp = x + (size_t)(b * (NA * 6) + a * 6) * PLANE + gh * NGW + gw;
        const float p0 = xp[0];
        const float p1 = xp[PLANE];
        const float p2 = xp[2 * PLANE];
        const float p3 = xp[3 * PLANE];
        const float p4 = xp[4 * PLANE];
        const float p5 = xp[5 * PLANE];

        const float cx    = 1.0f / (1.0f + expf(-p0));
        const float cy    = 1.0f / (1.0f + expf(-p1));
        const float pconf = 1.0f / (1.0f + expf(-p4));
        const float pcls  = 1.0f / (1.0f + expf(-p5));

        const float saw[3] = {1.25f, 2.0f, 4.125f};   // ANCHORS_PX / stride
        const float sah[3] = {1.625f, 3.75f, 2.875f};
        const float bx = cx + (float)gw;
        const float by = cy + (float)gh;
        const float bw = expf(p2) * saw[a];
        const float bh = expf(p3) * sah[a];

        float* o = out + (size_t)tid * 6;
        o[0] = bx * 8.0f; o[1] = by * 8.0f; o[2] = bw * 8.0f; o[3] = bh * 8.0f;
        o[4] = pconf;     o[5] = pcls;

        // normalized predicted box (xyxy) for ignore-IoU
        const float pxc = bx / (float)NGW, pyc = by / (float)NGH;
        const float pwn = bw / (float)NGW, phn = bh / (float)NGH;
        const float px1 = pxc - pwn * 0.5f, py1 = pyc - phn * 0.5f;
        const float px2 = pxc + pwn * 0.5f, py2 = pyc + phn * 0.5f;
        const float parea = pwn * phn;

        float best = -1.0f;
        int objt = -1;
        for (int t = 0; t < NT; ++t) {
            const float* s = st + t * 16;
            if ((int)s[0] != b) continue;   // wave-uniform skip (wave spans one image)
            const float iw = fmaxf(fminf(s[12], px2) - fmaxf(s[10], px1), 0.0f);
            const float ih = fmaxf(fminf(s[13], py2) - fmaxf(s[11], py1), 0.0f);
            const float inter = iw * ih;
            const float iou = inter / (((s[14] + parea) - inter) + 1e-16f);
            if (iou > best) best = iou;
            if (s[1] != 0.0f && (int)s[2] == a && (int)s[3] == gh && (int)s[4] == gw)
                objt = t;                   // last match wins (scatter order)
        }

        if (objt >= 0) {
            const float* s = st + objt * 16;
            const float sc = s[9], s2 = sc * sc;
            const float dx = cx - s[5], dy = cy - s[6];
            const float dw = p2 - s[7], dh = p3 - s[8];
            lxy   = (dx * dx + dy * dy) * s2;
            lwh   = (dw * dw + dh * dh) * s2;
            lconf = -fmaxf(logf(pconf), -100.0f);
            lcls  = -fmaxf(logf(pcls),  -100.0f);
        } else if (best <= 0.5f) {
            lconf = -fmaxf(logf(1.0f - pconf), -100.0f);
        }
    }

    // block reduction: wave shuffle then LDS across the 4 waves
    for (int off = 32; off > 0; off >>= 1) {
        lxy   += __shfl_down(lxy, off);
        lwh   += __shfl_down(lwh, off);
        lconf += __shfl_down(lconf, off);
        lcls  += __shfl_down(lcls, off);
    }
    __shared__ float red[4][4];
    const int lane = threadIdx.x & 63, wv = threadIdx.x >> 6;
    if (lane == 0) { red[wv][0] = lxy; red[wv][1] = lwh; red[wv][2] = lconf; red[wv][3] = lcls; }
    __syncthreads();
    if (threadIdx.x == 0) {
        float a0 = 0.f, a1 = 0.f, a2 = 0.f, a3 = 0.f;
        for (int w = 0; w < 4; ++w) { a0 += red[w][0]; a1 += red[w][1]; a2 += red[w][2]; a3 += red[w][3]; }
        atomicAdd(&lossbuf[1], a0);
        atomicAdd(&lossbuf[2], a1);
        atomicAdd(&lossbuf[3], a2);
        atomicAdd(&lossbuf[4], a3);
    }
}

// ---------------- Kernel 3: total ----------------
__global__ void yolo_final(float* __restrict__ lossbuf) {
    lossbuf[0] = ((lossbuf[1] + lossbuf[2]) + lossbuf[3]) + lossbuf[4];
}

extern "C" void kernel_launch(void* const* d_in, const int* in_sizes, int n_in,
                              void* d_out, int out_size, void* d_ws, size_t ws_size,
                              hipStream_t stream) {
    const float* x   = (const float*)d_in[0];
    const float* tgt = (const float*)d_in[1];
    float* out     = (float*)d_out;
    float* lossbuf = out + NOUT;          // [total, lxy, lwh, lconf, lcls]
    float* tinfo   = (float*)d_ws;        // 48*16 floats

    hipLaunchKernelGGL(yolo_prep,  dim3(1),           dim3(64),  0, stream, tgt, tinfo, lossbuf);
    hipLaunchKernelGGL(yolo_main,  dim3(NCELL / 256), dim3(256), 0, stream, x, tinfo, out, lossbuf);
    hipLaunchKernelGGL(yolo_final, dim3(1),           dim3(1),   0, stream, lossbuf);
}

// Round 2
// 19.925 us; speedup vs baseline: 6.6243x; 6.6243x over previous
//
#include <hip/hip_runtime.h>

#define NB 32
#define NA 3
#define NGH 76
#define NGW 76
#define NT 48
#define PLANE (NGH * NGW)         // 5776
#define NCELL (NB * NA * PLANE)   // 554496
#define NOUT  (NCELL * 6)         // 3326976
#define NBLK  (NCELL / 256)       // 2166

static_assert(NCELL % 256 == 0, "grid must divide evenly");

// st layout per target (16 floats):
// 0: timg  1: valid  2: bi  3: gj  4: gi  5: tx  6: ty  7: tw  8: th  9: sc
// 10..13: x1 y1 x2 y2 (normalized xyxy)  14: area  15: pad

__launch_bounds__(256)
__global__ void yolo_main(const float* __restrict__ x,
                          const float* __restrict__ tgt,
                          float* __restrict__ out,
                          float4* __restrict__ partials) {
    __shared__ float st[NT * 16];
    __shared__ unsigned long long sball[NB];
    __shared__ int soff[NB + 1];
    __shared__ int sord[NT];

    const int tx  = threadIdx.x;
    const int tid = blockIdx.x * 256 + tx;

    // ---------- decode (independent of targets; loads issue early) ----------
    const int gw = tid % NGW;
    const int gh = (tid / NGW) % NGH;
    const int a  = (tid / PLANE) % NA;
    const int b  = tid / (NA * PLANE);

    const float* xp = x + (size_t)(b * (NA * 6) + a * 6) * PLANE + gh * NGW + gw;
    const float p0 = xp[0];
    const float p1 = xp[PLANE];
    const float p2 = xp[2 * PLANE];
    const float p3 = xp[3 * PLANE];
    const float p4 = xp[4 * PLANE];
    const float p5 = xp[5 * PLANE];

    const float cx    = 1.0f / (1.0f + __expf(-p0));
    const float cy    = 1.0f / (1.0f + __expf(-p1));
    const float pconf = 1.0f / (1.0f + __expf(-p4));
    const float pcls  = 1.0f / (1.0f + __expf(-p5));

    // ANCHORS_PX / stride, via selects (avoid runtime-indexed array -> scratch)
    const float sa_w = (a == 0) ? 1.25f  : ((a == 1) ? 2.0f  : 4.125f);
    const float sa_h = (a == 0) ? 1.625f : ((a == 1) ? 3.75f : 2.875f);
    const float bx = cx + (float)gw;
    const float by = cy + (float)gh;
    const float bw = __expf(p2) * sa_w;
    const float bh = __expf(p3) * sa_h;

    float* o = out + (size_t)tid * 6;
    ((float2*)o)[0] = make_float2(bx * 8.0f, by * 8.0f);
    ((float2*)o)[1] = make_float2(bw * 8.0f, bh * 8.0f);
    ((float2*)o)[2] = make_float2(pconf, pcls);

    // ---------- wave 0: target prep + per-image CSR (ballot-based) ----------
    if (tx < 64) {
        const int t = tx;
        const bool isT = (t < NT);
        int timg = 999;                       // sentinel: matches no image
        if (isT) {
            const float t00 = tgt[0];
            const float* tr = tgt + t * 6;
            timg = (int)(tr[0] - t00);
            const float bxn = tr[1], byn = tr[2], bwn = tr[3], bhn = tr[4];

            const float gx = bxn * (float)NGW;
            const float gy = byn * (float)NGH;
            const int gi = (int)gx;
            const int gj = (int)gy;
            const float tarea = bwn * bhn;

            // anchor wh-IoU argmax over 9 anchors (first max wins, strict >)
            const float aw_px[9] = {10.f,16.f,33.f,30.f,62.f,59.f,116.f,156.f,373.f};
            const float ah_px[9] = {13.f,30.f,23.f,61.f,45.f,119.f,90.f,198.f,326.f};
            int bidx = 0; float biou = -1e30f;
            #pragma unroll
            for (int k = 0; k < 9; ++k) {
                const float aw = aw_px[k] / 608.0f;
                const float ah = ah_px[k] / 608.0f;
                const float wi = fminf(aw, bwn) * fminf(ah, bhn);
                const float un = ((aw * ah + 1e-16f) + tarea) - wi;
                const float iou = wi / un;
                if (iou > biou) { biou = iou; bidx = k; }
            }
            const bool inm = (bidx >= 0) && (bidx <= 2);
            const bool valid = inm && (gi < NGW) && (gj < NGH) && (gi >= 0) && (gj >= 0);
            const int bic = bidx < 0 ? 0 : (bidx > 2 ? 2 : bidx);
            const float apw = (bic == 0) ? 10.f : ((bic == 1) ? 16.f : 33.f);
            const float aph = (bic == 0) ? 13.f : ((bic == 1) ? 30.f : 23.f);

            float* s = st + t * 16;
            s[0]  = (float)timg;
            s[1]  = valid ? 1.0f : 0.0f;
            s[2]  = (float)bidx;
            s[3]  = (float)gj;
            s[4]  = (float)gi;
            s[5]  = gx - floorf(gx);
            s[6]  = gy - floorf(gy);
            s[7]  = __logf(((bwn * (float)NGW) * 8.0f) / apw + 1e-16f);
            s[8]  = __logf(((bhn * (float)NGH) * 8.0f) / aph + 1e-16f);
            s[9]  = 2.0f - bwn * bhn;
            s[10] = bxn - bwn * 0.5f;
            s[11] = byn - bhn * 0.5f;
            s[12] = bxn + bwn * 0.5f;
            s[13] = byn + bhn * 0.5f;
            s[14] = tarea;
            s[15] = 0.0f;
        }

        // per-image counts via 32 ballots (all 64 lanes participate)
        int cnt = 0;
        for (int bb = 0; bb < NB; ++bb) {
            const unsigned long long m = __ballot(timg == bb);
            if (t == 0) sball[bb] = m;
            if (t == bb) cnt = (int)__popcll(m);
        }
        // exclusive prefix over 32 counts (shuffle scan)
        int inc = cnt;
        #pragma unroll
        for (int d = 1; d < 32; d <<= 1) {
            const int v = __shfl_up(inc, d);
            if (t >= d) inc += v;
        }
        if (t < NB) soff[t] = inc - cnt;
        if (t == NB - 1) soff[NB] = inc;
        // stable order within image: rank = popcount of earlier lanes of same image
        if (isT) {
            const unsigned long long m = sball[timg];
            const int rank = (int)__popcll(m & ((1ULL << t) - 1ULL));
            sord[soff[timg] + rank] = t;
        }
    }
    __syncthreads();

    // ---------- per-cell losses over this image's targets only ----------
    float lxy = 0.f, lwh = 0.f, lconf = 0.f, lcls = 0.f;
    {
        const float pxc = bx * (1.0f / NGW), pyc = by * (1.0f / NGH);
        const float pwn = bw * (1.0f / NGW), phn = bh * (1.0f / NGH);
        const float px1 = pxc - pwn * 0.5f, py1 = pyc - phn * 0.5f;
        const float px2 = pxc + pwn * 0.5f, py2 = pyc + phn * 0.5f;
        const float parea = pwn * phn;

        float best = -1.0f;
        const float* sobj = nullptr;
        const int j1 = soff[b + 1];
        for (int j = soff[b]; j < j1; ++j) {
            const float* s = st + sord[j] * 16;
            const float iw = fmaxf(fminf(s[12], px2) - fmaxf(s[10], px1), 0.0f);
            const float ih = fmaxf(fminf(s[13], py2) - fmaxf(s[11], py1), 0.0f);
            const float inter = iw * ih;
            const float iou = inter / (((s[14] + parea) - inter) + 1e-16f);
            if (iou > best) best = iou;
            if (s[1] != 0.0f && (int)s[2] == a && (int)s[3] == gh && (int)s[4] == gw)
                sobj = s;                      // last match wins (scatter order)
        }

        if (sobj) {
            const float sc = sobj[9], s2 = sc * sc;
            const float dx = cx - sobj[5], dy = cy - sobj[6];
            const float dw = p2 - sobj[7], dh = p3 - sobj[8];
            lxy   = (dx * dx + dy * dy) * s2;
            lwh   = (dw * dw + dh * dh) * s2;
            lconf = -fmaxf(__logf(pconf), -100.0f);
            lcls  = -fmaxf(__logf(pcls),  -100.0f);
        } else if (best <= 0.5f) {
            lconf = -fmaxf(__logf(1.0f - pconf), -100.0f);
        }
    }

    // ---------- block reduction -> per-block partial (NO atomics) ----------
    #pragma unroll
    for (int off = 32; off > 0; off >>= 1) {
        lxy   += __shfl_down(lxy, off);
        lwh   += __shfl_down(lwh, off);
        lconf += __shfl_down(lconf, off);
        lcls  += __shfl_down(lcls, off);
    }
    __shared__ float red[4][4];
    const int lane = tx & 63, wv = tx >> 6;
    if (lane == 0) { red[wv][0] = lxy; red[wv][1] = lwh; red[wv][2] = lconf; red[wv][3] = lcls; }
    __syncthreads();
    if (tx == 0) {
        float a0 = 0.f, a1 = 0.f, a2 = 0.f, a3 = 0.f;
        #pragma unroll
        for (int w = 0; w < 4; ++w) { a0 += red[w][0]; a1 += red[w][1]; a2 += red[w][2]; a3 += red[w][3]; }
        partials[blockIdx.x] = make_float4(a0, a1, a2, a3);
    }
}

// ---------------- final reduction: 2166 partials -> 5 scalars ----------------
__launch_bounds__(256)
__global__ void yolo_final(const float4* __restrict__ partials,
                           float* __restrict__ lossbuf) {
    float a0 = 0.f, a1 = 0.f, a2 = 0.f, a3 = 0.f;
    for (int i = threadIdx.x; i < NBLK; i += 256) {
        const float4 p = partials[i];
        a0 += p.x; a1 += p.y; a2 += p.z; a3 += p.w;
    }
    #pragma unroll
    for (int off = 32; off > 0; off >>= 1) {
        a0 += __shfl_down(a0, off);
        a1 += __shfl_down(a1, off);
        a2 += __shfl_down(a2, off);
        a3 += __shfl_down(a3, off);
    }
    __shared__ float red[4][4];
    const int lane = threadIdx.x & 63, wv = threadIdx.x >> 6;
    if (lane == 0) { red[wv][0] = a0; red[wv][1] = a1; red[wv][2] = a2; red[wv][3] = a3; }
    __syncthreads();
    if (threadIdx.x == 0) {
        float s0 = 0.f, s1 = 0.f, s2 = 0.f, s3 = 0.f;
        #pragma unroll
        for (int w = 0; w < 4; ++w) { s0 += red[w][0]; s1 += red[w][1]; s2 += red[w][2]; s3 += red[w][3]; }
        lossbuf[1] = s0;
        lossbuf[2] = s1;
        lossbuf[3] = s2;
        lossbuf[4] = s3;
        lossbuf[0] = ((s0 + s1) + s2) + s3;
    }
}

extern "C" void kernel_launch(void* const* d_in, const int* in_sizes, int n_in,
                              void* d_out, int out_size, void* d_ws, size_t ws_size,
                              hipStream_t stream) {
    const float* x   = (const float*)d_in[0];
    const float* tgt = (const float*)d_in[1];
    float* out      = (float*)d_out;
    float* lossbuf  = out + NOUT;            // [total, lxy, lwh, lconf, lcls]
    float4* partial = (float4*)d_ws;         // NBLK float4s = 34.7 KB

    hipLaunchKernelGGL(yolo_main,  dim3(NBLK), dim3(256), 0, stream, x, tgt, out, partial);
    hipLaunchKernelGGL(yolo_final, dim3(1),    dim3(256), 0, stream, partial, out + NOUT);
    (void)lossbuf; (void)in_sizes; (void)n_in; (void)out_size; (void)ws_size;
}

// Round 3
// 17.211 us; speedup vs baseline: 7.6689x; 1.1577x over previous
//
#include <hip/hip_runtime.h>

#define NB 32
#define NA 3
#define NGH 76
#define NGW 76
#define NT 48
#define PLANE (NGH * NGW)          // 5776
#define NCELL (NB * NA * PLANE)    // 554496
#define NOUT  (NCELL * 6)          // 3326976
#define CPT 4                      // cells per thread
#define BLK 128
#define NTHREAD (NCELL / CPT)      // 138624
#define NBLK2 (NTHREAD / BLK)      // 1083

static_assert(NTHREAD % BLK == 0, "grid must divide evenly");
static_assert(PLANE % CPT == 0, "4 consecutive cells stay in one plane row-chunk");

// st layout per target (16 floats):
// 0: timg  1: valid  2: bi  3: gj  4: gi  5: tx  6: ty  7: tw  8: th  9: sc
// 10..13: x1 y1 x2 y2 (normalized xyxy)  14: area  15: pad

__launch_bounds__(BLK)
__global__ void yolo_main(const float* __restrict__ x,
                          const float* __restrict__ tgt,
                          float* __restrict__ out,
                          float4* __restrict__ partials) {
    __shared__ float st[NT * 16];
    __shared__ unsigned long long sball[NB];
    __shared__ int soff[NB + 1];
    __shared__ int sord[NT];

    const int tx  = threadIdx.x;
    const int tid = blockIdx.x * BLK + tx;
    const int g   = tid * CPT;                // first of 4 consecutive cells

    const int gw0 = g % NGW;
    const int gh  = (g / NGW) % NGH;
    const int a   = (g / PLANE) % NA;
    const int b   = g / (NA * PLANE);

    // ---------- vectorized channel loads (issue before target prep) ----------
    const float* xp = x + (size_t)(b * (NA * 6) + a * 6) * PLANE + (g % PLANE);
    const float4 v0 = *(const float4*)(xp);
    const float4 v1 = *(const float4*)(xp + PLANE);
    const float4 v2 = *(const float4*)(xp + 2 * PLANE);
    const float4 v3 = *(const float4*)(xp + 3 * PLANE);
    const float4 v4 = *(const float4*)(xp + 4 * PLANE);
    const float4 v5 = *(const float4*)(xp + 5 * PLANE);

    // ---------- wave 0: target prep + per-image CSR (ballot-based) ----------
    if (tx < 64) {
        const int t = tx;
        const bool isT = (t < NT);
        int timg = 999;                       // sentinel: matches no image
        if (isT) {
            const float t00 = tgt[0];
            const float* tr = tgt + t * 6;
            timg = (int)(tr[0] - t00);
            const float bxn = tr[1], byn = tr[2], bwn = tr[3], bhn = tr[4];

            const float gx = bxn * (float)NGW;
            const float gy = byn * (float)NGH;
            const int gi = (int)gx;
            const int gj = (int)gy;
            const float tarea = bwn * bhn;

            const float aw_px[9] = {10.f,16.f,33.f,30.f,62.f,59.f,116.f,156.f,373.f};
            const float ah_px[9] = {13.f,30.f,23.f,61.f,45.f,119.f,90.f,198.f,326.f};
            int bidx = 0; float biou = -1e30f;
            #pragma unroll
            for (int k = 0; k < 9; ++k) {
                const float aw = aw_px[k] / 608.0f;
                const float ah = ah_px[k] / 608.0f;
                const float wi = fminf(aw, bwn) * fminf(ah, bhn);
                const float un = ((aw * ah + 1e-16f) + tarea) - wi;
                const float iou = wi / un;
                if (iou > biou) { biou = iou; bidx = k; }
            }
            const bool inm = (bidx >= 0) && (bidx <= 2);
            const bool valid = inm && (gi < NGW) && (gj < NGH) && (gi >= 0) && (gj >= 0);
            const int bic = bidx < 0 ? 0 : (bidx > 2 ? 2 : bidx);
            const float apw = (bic == 0) ? 10.f : ((bic == 1) ? 16.f : 33.f);
            const float aph = (bic == 0) ? 13.f : ((bic == 1) ? 30.f : 23.f);

            float* s = st + t * 16;
            s[0]  = (float)timg;
            s[1]  = valid ? 1.0f : 0.0f;
            s[2]  = (float)bidx;
            s[3]  = (float)gj;
            s[4]  = (float)gi;
            s[5]  = gx - floorf(gx);
            s[6]  = gy - floorf(gy);
            s[7]  = __logf(((bwn * (float)NGW) * 8.0f) / apw + 1e-16f);
            s[8]  = __logf(((bhn * (float)NGH) * 8.0f) / aph + 1e-16f);
            s[9]  = 2.0f - bwn * bhn;
            s[10] = bxn - bwn * 0.5f;
            s[11] = byn - bhn * 0.5f;
            s[12] = bxn + bwn * 0.5f;
            s[13] = byn + bhn * 0.5f;
            s[14] = tarea;
            s[15] = 0.0f;
        }

        int cnt = 0;
        for (int bb = 0; bb < NB; ++bb) {
            const unsigned long long m = __ballot(timg == bb);
            if (t == 0) sball[bb] = m;
            if (t == bb) cnt = (int)__popcll(m);
        }
        int inc = cnt;
        #pragma unroll
        for (int d = 1; d < 32; d <<= 1) {
            const int v = __shfl_up(inc, d);
            if (t >= d) inc += v;
        }
        if (t < NB) soff[t] = inc - cnt;
        if (t == NB - 1) soff[NB] = inc;
        if (isT) {
            const unsigned long long m = sball[timg];
            const int rank = (int)__popcll(m & ((1ULL << t) - 1ULL));
            sord[soff[timg] + rank] = t;
        }
    }

    // ---------- decode 4 cells (fully unrolled, all static indices) ----------
    const float p0[CPT] = {v0.x, v0.y, v0.z, v0.w};
    const float p1[CPT] = {v1.x, v1.y, v1.z, v1.w};
    const float p2[CPT] = {v2.x, v2.y, v2.z, v2.w};
    const float p3[CPT] = {v3.x, v3.y, v3.z, v3.w};
    const float p4[CPT] = {v4.x, v4.y, v4.z, v4.w};
    const float p5[CPT] = {v5.x, v5.y, v5.z, v5.w};

    const float sa_w = (a == 0) ? 1.25f  : ((a == 1) ? 2.0f  : 4.125f);
    const float sa_h = (a == 0) ? 1.625f : ((a == 1) ? 3.75f : 2.875f);

    float cxv[CPT], cyv[CPT], pcf[CPT], pcl[CPT];
    float px1[CPT], py1[CPT], px2[CPT], py2[CPT], par[CPT];
    float o24[CPT * 6];

    #pragma unroll
    for (int c = 0; c < CPT; ++c) {
        const float cx    = 1.0f / (1.0f + __expf(-p0[c]));
        const float cy    = 1.0f / (1.0f + __expf(-p1[c]));
        const float pconf = 1.0f / (1.0f + __expf(-p4[c]));
        const float pcls  = 1.0f / (1.0f + __expf(-p5[c]));
        const float bx = cx + (float)(gw0 + c);
        const float by = cy + (float)gh;
        const float bw = __expf(p2[c]) * sa_w;
        const float bh = __expf(p3[c]) * sa_h;

        o24[c * 6 + 0] = bx * 8.0f;
        o24[c * 6 + 1] = by * 8.0f;
        o24[c * 6 + 2] = bw * 8.0f;
        o24[c * 6 + 3] = bh * 8.0f;
        o24[c * 6 + 4] = pconf;
        o24[c * 6 + 5] = pcls;

        const float pxc = bx * (1.0f / NGW), pyc = by * (1.0f / NGH);
        const float pwn = bw * (1.0f / NGW), phn = bh * (1.0f / NGH);
        cxv[c] = cx; cyv[c] = cy; pcf[c] = pconf; pcl[c] = pcls;
        px1[c] = pxc - pwn * 0.5f; py1[c] = pyc - phn * 0.5f;
        px2[c] = pxc + pwn * 0.5f; py2[c] = pyc + phn * 0.5f;
        par[c] = pwn * phn;
    }

    // ---------- coalesced output: 96 contiguous bytes per thread ----------
    {
        float4* ob = (float4*)(out + (size_t)g * 6);
        #pragma unroll
        for (int k = 0; k < 6; ++k)
            ob[k] = make_float4(o24[4 * k], o24[4 * k + 1], o24[4 * k + 2], o24[4 * k + 3]);
    }

    __syncthreads();

    // ---------- per-cell losses over this image's targets only ----------
    float best[CPT] = {-1.f, -1.f, -1.f, -1.f};
    int   so[CPT]   = {-1, -1, -1, -1};
    {
        const int j1 = soff[b + 1];
        for (int j = soff[b]; j < j1; ++j) {
            const int t = sord[j];
            const float* s = st + t * 16;          // LDS broadcast reads
            const float s1 = s[1], s2f = s[2], s3f = s[3], s4f = s[4];
            const float x1 = s[10], y1 = s[11], x2 = s[12], y2 = s[13], ta = s[14];
            const bool vmatch = (s1 != 0.0f) && ((int)s2f == a) && ((int)s3f == gh);
            #pragma unroll
            for (int c = 0; c < CPT; ++c) {
                const float iw = fmaxf(fminf(x2, px2[c]) - fmaxf(x1, px1[c]), 0.0f);
                const float ih = fmaxf(fminf(y2, py2[c]) - fmaxf(y1, py1[c]), 0.0f);
                const float inter = iw * ih;
                const float iou = inter / (((ta + par[c]) - inter) + 1e-16f);
                if (iou > best[c]) best[c] = iou;
                if (vmatch && ((int)s4f == gw0 + c)) so[c] = t;   // last match wins
            }
        }
    }

    float lxy = 0.f, lwh = 0.f, lconf = 0.f, lcls = 0.f;
    #pragma unroll
    for (int c = 0; c < CPT; ++c) {
        if (so[c] >= 0) {
            const float* s = st + so[c] * 16;
            const float sc = s[9], s2 = sc * sc;
            const float dx = cxv[c] - s[5], dy = cyv[c] - s[6];
            const float dw = p2[c] - s[7], dh = p3[c] - s[8];
            lxy   += (dx * dx + dy * dy) * s2;
            lwh   += (dw * dw + dh * dh) * s2;
            lconf += -fmaxf(__logf(pcf[c]), -100.0f);
            lcls  += -fmaxf(__logf(pcl[c]), -100.0f);
        } else if (best[c] <= 0.5f) {
            lconf += -fmaxf(__logf(1.0f - pcf[c]), -100.0f);
        }
    }

    // ---------- block reduction -> per-block partial ----------
    #pragma unroll
    for (int off = 32; off > 0; off >>= 1) {
        lxy   += __shfl_down(lxy, off);
        lwh   += __shfl_down(lwh, off);
        lconf += __shfl_down(lconf, off);
        lcls  += __shfl_down(lcls, off);
    }
    __shared__ float red[2][4];
    const int lane = tx & 63, wv = tx >> 6;
    if (lane == 0) { red[wv][0] = lxy; red[wv][1] = lwh; red[wv][2] = lconf; red[wv][3] = lcls; }
    __syncthreads();
    if (tx == 0) {
        partials[blockIdx.x] = make_float4(red[0][0] + red[1][0], red[0][1] + red[1][1],
                                           red[0][2] + red[1][2], red[0][3] + red[1][3]);
    }
}

// ---------------- final reduction: 1083 partials -> 5 scalars ----------------
__launch_bounds__(256)
__global__ void yolo_final(const float4* __restrict__ partials,
                           float* __restrict__ lossbuf) {
    float a0 = 0.f, a1 = 0.f, a2 = 0.f, a3 = 0.f;
    for (int i = threadIdx.x; i < NBLK2; i += 256) {
        const float4 p = partials[i];
        a0 += p.x; a1 += p.y; a2 += p.z; a3 += p.w;
    }
    #pragma unroll
    for (int off = 32; off > 0; off >>= 1) {
        a0 += __shfl_down(a0, off);
        a1 += __shfl_down(a1, off);
        a2 += __shfl_down(a2, off);
        a3 += __shfl_down(a3, off);
    }
    __shared__ float red[4][4];
    const int lane = threadIdx.x & 63, wv = threadIdx.x >> 6;
    if (lane == 0) { red[wv][0] = a0; red[wv][1] = a1; red[wv][2] = a2; red[wv][3] = a3; }
    __syncthreads();
    if (threadIdx.x == 0) {
        float s0 = 0.f, s1 = 0.f, s2 = 0.f, s3 = 0.f;
        #pragma unroll
        for (int w = 0; w < 4; ++w) { s0 += red[w][0]; s1 += red[w][1]; s2 += red[w][2]; s3 += red[w][3]; }
        lossbuf[1] = s0;
        lossbuf[2] = s1;
        lossbuf[3] = s2;
        lossbuf[4] = s3;
        lossbuf[0] = ((s0 + s1) + s2) + s3;
    }
}

extern "C" void kernel_launch(void* const* d_in, const int* in_sizes, int n_in,
                              void* d_out, int out_size, void* d_ws, size_t ws_size,
                              hipStream_t stream) {
    const float* x   = (const float*)d_in[0];
    const float* tgt = (const float*)d_in[1];
    float* out      = (float*)d_out;
    float4* partial = (float4*)d_ws;           // 1083 float4s = 17.3 KB

    hipLaunchKernelGGL(yolo_main,  dim3(NBLK2), dim3(BLK), 0, stream, x, tgt, out, partial);
    hipLaunchKernelGGL(yolo_final, dim3(1),     dim3(256), 0, stream, partial, out + NOUT);
    (void)in_sizes; (void)n_in; (void)out_size; (void)ws_size;
}